// Round 6
// baseline (291.546 us; speedup 1.0000x reference)
//
#include <hip/hip_runtime.h>
#include <hip/hip_cooperative_groups.h>
#include <math.h>

namespace cg = cooperative_groups;

#define NBOX   16384
#define NPRE   1024
#define NPOST  512
#define NMS_TH 0.8f
#define DEN_EPS 1e-8f
#define NCAND  2048          // top-k candidate buffer
#define NBUCK  8192          // 13-bit histogram buckets
#define GRIDB  256           // cooperative grid blocks (1/CU guaranteed resident)
#define BLK    256
#define WMAX   (1u << 20)    // >= B*NPRE*(NPRE-1)/2 worst case (1,047,552)
#define ROWCAP 128           // LDS-prefetched NMS rows (16 KB / 16 words)

typedef unsigned long long ull;

__device__ __forceinline__ unsigned mono_f32(float a) {
  unsigned u = __float_as_uint(a);
  return (u & 0x80000000u) ? ~u : (u | 0x80000000u);
}

// ---------------- exact rotated IoU > thresh, register-only ------------------
// Stable argsort by (angle, idx) == successor chain on key=(mono(ang)<<5)|idx;
// polygon area = sum of cross(p, succ(p)), wrap to global min key.
__device__ bool iou_exact_gt(const float* __restrict__ Ab, const float* __restrict__ Bb) {
  float ax = Ab[0], ay = Ab[1], bx = Bb[0], by = Bb[1];
  float aA = Ab[15], aB = Bb[15];
  float acx[4], acy[4], bcx[4], bcy[4];
#pragma unroll
  for (int k = 0; k < 4; ++k) {
    acx[k] = Ab[6 + k]; acy[k] = Ab[10 + k];
    bcx[k] = Bb[6 + k]; bcy[k] = Bb[10 + k];
  }
  float px[24], py[24];
  bool act[24];
#pragma unroll
  for (int p = 0; p < 4; ++p) {
    float A0x = acx[p], A0y = acy[p];
    float DAx = acx[(p + 1) & 3] - A0x, DAy = acy[(p + 1) & 3] - A0y;
#pragma unroll
    for (int q = 0; q < 4; ++q) {
      float B0x = bcx[q], B0y = bcy[q];
      float DBx = bcx[(q + 1) & 3] - B0x, DBy = bcy[(q + 1) & 3] - B0y;
      float den = DAx * DBy - DAy * DBx;
      float dxx = B0x - A0x, dyy = B0y - A0y;
      bool dok = fabsf(den) > DEN_EPS;
      float dens = dok ? den : 1.0f;
      float t = (dxx * DBy - dyy * DBx) / dens;
      float u = (dxx * DAy - dyy * DAx) / dens;
      int k = p * 4 + q;
      px[k] = A0x + t * DAx;
      py[k] = A0y + t * DAy;
      act[k] = dok && t >= 0.f && t <= 1.f && u >= 0.f && u <= 1.f;
    }
  }
  float cA = Ab[4], sA = Ab[5], cB = Bb[4], sB = Bb[5];
#pragma unroll
  for (int k = 0; k < 4; ++k) {       // corners of A in B
    float rx = acx[k] - bx, ry = acy[k] - by;
    float qx =  rx * cB + ry * sB, qy = -rx * sB + ry * cB;
    px[16 + k] = acx[k]; py[16 + k] = acy[k];
    act[16 + k] = (fabsf(qx) <= Bb[2] * 0.5f + 1e-5f) && (fabsf(qy) <= Bb[3] * 0.5f + 1e-5f);
  }
#pragma unroll
  for (int k = 0; k < 4; ++k) {       // corners of B in A
    float rx = bcx[k] - ax, ry = bcy[k] - ay;
    float qx =  rx * cA + ry * sA, qy = -rx * sA + ry * cA;
    px[20 + k] = bcx[k]; py[20 + k] = bcy[k];
    act[20 + k] = (fabsf(qx) <= Ab[2] * 0.5f + 1e-5f) && (fabsf(qy) <= Ab[3] * 0.5f + 1e-5f);
  }
  int cnt = 0; float sx = 0.f, sy = 0.f;
#pragma unroll
  for (int k = 0; k < 24; ++k)
    if (act[k]) { cnt++; sx += px[k]; sy += py[k]; }
  float fc = (float)(cnt > 1 ? cnt : 1);
  float cx0 = sx / fc, cy0 = sy / fc;
  ull key[24];
#pragma unroll
  for (int k = 0; k < 24; ++k) {
    float ang = atan2f(py[k] - cy0, px[k] - cx0);
    key[k] = act[k] ? ((((ull)mono_f32(ang)) << 5) | (ull)k) : ~0ull;
  }
  ull kmin = ~0ull; float fx = 0.f, fy = 0.f;
#pragma unroll
  for (int k = 0; k < 24; ++k) {
    bool lt = key[k] < kmin;
    kmin = lt ? key[k] : kmin;
    fx = lt ? px[k] : fx;
    fy = lt ? py[k] : fy;
  }
  float ssum = 0.f;
#pragma unroll
  for (int k = 0; k < 24; ++k) {
    ull myk = key[k];
    ull best = ~0ull; float nx = fx, ny = fy;   // default: wrap to first
#pragma unroll
    for (int j = 0; j < 24; ++j) {
      bool c = (key[j] > myk) && (key[j] < best);
      best = c ? key[j] : best;
      nx = c ? px[j] : nx;
      ny = c ? py[j] : ny;
    }
    float contrib = px[k] * ny - py[k] * nx;
    ssum += (myk != ~0ull) ? contrib : 0.f;
  }
  float inter = 0.5f * fabsf(ssum);
  float uni = aA + aB - inter;
  return inter / fmaxf(uni, 1e-6f) > NMS_TH;
}

struct Params {
  const float* box; const float* cls; float* out;
  ull* keys; unsigned* hist; ull* cand; unsigned* candCnt;
  int* topi; float* binfo; float4* pinfo; ull* mask; unsigned* nz;
  unsigned* wl; unsigned* wcnt; unsigned wcap; int B;
};

__global__ __launch_bounds__(BLK) void k_all(Params P) {
  cg::grid_group grid = cg::this_grid();
  const int tid = threadIdx.x;
  const int bid = blockIdx.x;
  const int gid = bid * BLK + tid;
  const int lane = tid & 63;
  const int wv = tid >> 6;
  const int B = P.B;
  const int nkeys = B * NBOX;

  __shared__ ull lk[NCAND];            // 16 KB scratch, reused per phase
  __shared__ unsigned smallu[16];
  __shared__ ull remv_sh[16];
  __shared__ unsigned rlist[ROWCAP];
  __shared__ unsigned rn_sh;

  // ============ P0z: zero hist / nz / counters ============
  for (int x = gid; x < B * NBUCK; x += GRIDB * BLK) P.hist[x] = 0u;
  for (int x = gid; x < B * NPRE; x += GRIDB * BLK) P.nz[x] = 0u;
  if (gid < B) P.candCnt[gid] = 0u;
  if (gid == B) P.wcnt[0] = 0u;
  grid.sync();

  // ============ P0k: keys + global histogram ============
  if (gid < nkeys) {
    const float* cc = P.cls + (size_t)gid * 3;
    float s = fmaxf(cc[0], fmaxf(cc[1], cc[2]));
    unsigned u = mono_f32(s);
    int i = gid & (NBOX - 1);
    int b = gid >> 14;
    P.keys[gid] = ((ull)u << 14) | (ull)(16383 - i);
    atomicAdd(&P.hist[b * NBUCK + (u >> 19)], 1u);
  }
  grid.sync();

  // ============ P12: per-block redundant threshold + ballot compact ============
  if (gid < nkeys) {                   // block-uniform (NBOX % BLK == 0)
    int b = gid >> 14;
    const unsigned* hb = P.hist + b * NBUCK;
    // chunk = 32 buckets/thread; inclusive suffix scan of chunk sums
    unsigned csum = 0;
#pragma unroll 8
    for (int k = 0; k < 32; ++k) csum += hb[tid * 32 + k];
    unsigned v = csum;
#pragma unroll
    for (int off = 1; off < 64; off <<= 1) {
      unsigned o = __shfl_down((int)v, off, 64);
      if (lane + off < 64) v += o;
    }
    if (lane == 0) smallu[wv] = v;
    __syncthreads();
    unsigned shi = 0;
    for (int w2 = wv + 1; w2 < 4; ++w2) shi += smallu[w2];
    unsigned incl = v + shi;           // suffix including this thread's chunk
    unsigned safter = incl - csum;     // suffix of strictly-higher chunks
    if (safter < NPRE && incl >= NPRE) {   // unique crossing chunk
      unsigned c = safter;
      for (int k = 31; k >= 0; --k) {
        c += hb[tid * 32 + k];
        if (c >= NPRE) { smallu[8] = (unsigned)(tid * 32 + k); break; }
      }
    }
    __syncthreads();
    unsigned T = smallu[8];
    ull key = P.keys[gid];
    bool c = (unsigned)(key >> 33) >= T;
    ull bal = __ballot(c);
    if (bal) {
      unsigned base = 0;
      if (lane == 0) base = atomicAdd(&P.candCnt[b], (unsigned)__popcll(bal));
      base = (unsigned)__shfl((int)base, 0, 64);
      if (c) {
        unsigned pos = base + (unsigned)__popcll(bal & ((1ull << lane) - 1ull));
        if (pos < NCAND) P.cand[(size_t)b * NCAND + pos] = key;
      }
    }
  }
  grid.sync();

  // ============ P3: rank candidates -> topi, binfo, pinfo ============
  if (bid < B * 8) {
    int b = bid >> 3;
    int j = (bid & 7) * BLK + tid;     // 0..2047
    unsigned C = P.candCnt[b]; if (C > NCAND) C = NCAND;
#pragma unroll
    for (int k = 0; k < NCAND / BLK; ++k) {
      int idx = k * BLK + tid;
      lk[idx] = ((unsigned)idx < C) ? P.cand[(size_t)b * NCAND + idx] : 0ULL;
    }
    __syncthreads();
    ull my = ((unsigned)j < C) ? lk[j] : 0ULL;
    int r = 0;
    const ulonglong2* p2 = (const ulonglong2*)lk;
#pragma unroll 8
    for (int k = 0; k < NCAND / 2; ++k) {
      ulonglong2 kk = p2[k];
      r += (kk.x > my) ? 1 : 0;
      r += (kk.y > my) ? 1 : 0;
    }
    if ((unsigned)j < C && r < NPRE) {
      int i = 16383 - (int)(my & 0x3FFFULL);
      P.topi[b * NPRE + r] = i;
      const float* bp = P.box + ((size_t)b * NBOX + i) * 7;
      float x = bp[0], y = bp[1], dx = bp[3], dy = bp[4], ry = bp[6];
      float cth = cosf(ry), sth = sinf(ry);
      float* o = P.binfo + ((size_t)b * NPRE + r) * 16;
      o[0] = x; o[1] = y; o[2] = dx; o[3] = dy; o[4] = cth; o[5] = sth;
      const float offx[4] = {0.5f, -0.5f, -0.5f, 0.5f};
      const float offy[4] = {0.5f, 0.5f, -0.5f, -0.5f};
#pragma unroll
      for (int k = 0; k < 4; ++k) {
        float lx = dx * offx[k], ly = dy * offy[k];
        o[6 + k]  = x + lx * cth - ly * sth;
        o[10 + k] = y + lx * sth + ly * cth;
      }
      float rad = 0.5f * sqrtf(dx * dx + dy * dy);
      float area = dx * dy;
      o[14] = rad; o[15] = area;
      P.pinfo[(size_t)b * NPRE + r] = make_float4(x, y, rad, area);
    }
  }
  grid.sync();

  // ============ P4: cheap rejects -> worklist (+ mask-word pre-zero) ============
  {
    int nwords = B * NPRE * 16;
    for (int wt = bid * (BLK / 64) + wv; wt < nwords; wt += GRIDB * (BLK / 64)) {
      int w = wt & 15;
      int i = (wt >> 4) & (NPRE - 1);
      int b = wt >> 14;
      if (w * 64 + 63 <= i) continue;
      int j = w * 64 + lane;
      float4 pj = P.pinfo[(size_t)b * NPRE + j];
      float4 pi = P.pinfo[(size_t)b * NPRE + i];
      bool cnd = false;
      if (j > i) {
        float ddx = pi.x - pj.x, ddy = pi.y - pj.y;
        float rr = pi.z + pj.z + 1e-3f;
        if (ddx * ddx + ddy * ddy <= rr * rr) {
          float mn = fminf(pi.w, pj.w), mx = fmaxf(pi.w, pj.w);
          if (mn > NMS_TH * mx) cnd = true;
        }
      }
      ull bal = __ballot(cnd);
      if (!bal) continue;
      unsigned base = 0;
      if (lane == 0) {
        P.mask[((size_t)b * NPRE + i) * 16 + w] = 0ull;   // pre-zero, nz-gated
        base = atomicAdd(P.wcnt, (unsigned)__popcll(bal));
      }
      base = (unsigned)__shfl((int)base, 0, 64);
      if (cnd) {
        unsigned off = base + (unsigned)__popcll(bal & ((1ull << lane) - 1ull));
        if (off < P.wcap)
          P.wl[off] = ((unsigned)b << 20) | ((unsigned)i << 10) | (unsigned)j;
      }
    }
  }
  grid.sync();

  // ============ P5: exact IoU over dense worklist ============
  {
    unsigned n = P.wcnt[0];
    if (n > P.wcap) n = P.wcap;
    for (unsigned e = (unsigned)gid; e < n; e += GRIDB * BLK) {
      unsigned pk = P.wl[e];
      unsigned b = pk >> 20, i = (pk >> 10) & 1023, j = pk & 1023;
      const float* base = P.binfo + (size_t)b * NPRE * 16;
      if (iou_exact_gt(base + (size_t)i * 16, base + (size_t)j * 16)) {
        atomicOr(&P.mask[((size_t)b * NPRE + i) * 16 + (j >> 6)], 1ull << (j & 63));
        atomicOr(&P.nz[b * NPRE + i], 1u << (j >> 6));
      }
    }
  }
  grid.sync();

  // ============ P67: per-batch NMS (LDS-prefetched) + compact + gather ========
  if (bid < B) {
    int b = bid;
    ull rfr[16];
    if (wv == 0) {                     // wave 0: interesting-row bitmaps + list
#pragma unroll
      for (int w = 0; w < 16; ++w) {
        unsigned vz = P.nz[b * NPRE + w * 64 + lane];
        rfr[w] = __ballot(vz != 0u);
      }
      if (lane == 0) {
        unsigned n = 0;
        for (int w = 0; w < 16; ++w) {
          ull bb = rfr[w];
          while (bb) {
            int ii = __ffsll(bb) - 1;
            bb &= bb - 1;
            if (n < ROWCAP) rlist[n] = (unsigned)(w * 64 + ii);
            n++;
          }
        }
        rn_sh = n;
      }
    }
    __syncthreads();
    unsigned rn = rn_sh;
    unsigned rpf = rn < ROWCAP ? rn : ROWCAP;
    // all 4 waves prefetch mask words for listed rows into lk
    for (unsigned s = (unsigned)(tid >> 4); s < rpf; s += BLK / 16) {
      unsigned row = rlist[s];
      int wd = tid & 15;
      unsigned nzi = P.nz[b * NPRE + row];
      lk[s * 16 + wd] = ((nzi >> wd) & 1u)
                        ? P.mask[((size_t)b * NPRE + row) * 16 + wd] : 0ull;
    }
    __syncthreads();
    if (wv == 0) {                     // wave 0: serial greedy walk (LDS speed)
      ull remv = 0;                    // lane w<16 holds remv word w
      for (unsigned s = 0; s < rn; ++s) {
        unsigned row;
        ull m;
        if (s < ROWCAP) {
          row = rlist[s];
          m = (lane < 16) ? lk[s * 16 + lane] : 0ull;
        } else {                       // overflow: recompute row, global reads
          // find s-th interesting row (rare path; never at bench density)
          unsigned cnt2 = 0; row = 0;
          for (int w = 0; w < 16 && cnt2 <= s; ++w) {
            ull bb = __ballot(P.nz[b * NPRE + w * 64 + lane] != 0u);
            unsigned pc = (unsigned)__popcll(bb);
            if (cnt2 + pc > s) {
              unsigned need = s - cnt2;
              ull t2 = bb;
              for (unsigned q = 0; q < need; ++q) t2 &= t2 - 1;
              row = w * 64 + (__ffsll(t2) - 1);
              cnt2 = s + 1; break;
            }
            cnt2 += pc;
          }
          unsigned nzi = P.nz[b * NPRE + row];
          m = (lane < 16 && ((nzi >> lane) & 1u))
              ? P.mask[((size_t)b * NPRE + row) * 16 + lane] : 0ull;
        }
        int w = row >> 6, ii = row & 63;
        ull rw = __shfl(remv, w, 64);
        if (!((rw >> ii) & 1ULL)) remv |= m;
      }
      if (lane < 16) remv_sh[lane] = remv;
    }
    __syncthreads();

    // compact + gather: 256 threads x 4 contiguous slots
    int p0 = tid * 4;
    ull rw = remv_sh[p0 >> 6];
    int a0 = !((rw >> ((p0 + 0) & 63)) & 1ULL);
    int a1 = !((rw >> ((p0 + 1) & 63)) & 1ULL);
    int a2 = !((rw >> ((p0 + 2) & 63)) & 1ULL);
    int a3 = !((rw >> ((p0 + 3) & 63)) & 1ULL);
    int myc = a0 + a1 + a2 + a3;
    int v = myc;
#pragma unroll
    for (int off = 1; off < 64; off <<= 1) {
      int t2 = __shfl_up(v, off, 64);
      if (lane >= off) v += t2;
    }
    if (lane == 63) smallu[wv] = (unsigned)v;
    __syncthreads();
    int pre = 0;
    for (int w2 = 0; w2 < wv; ++w2) pre += (int)smallu[w2];
    int total = (int)(smallu[0] + smallu[1] + smallu[2] + smallu[3]);
    int s = pre + v - myc;

    float* rois   = P.out;
    float* scores = P.out + (size_t)B * NPOST * 7;
    float* labels = scores + (size_t)B * NPOST;
    float* logits = labels + (size_t)B * NPOST;
    int aa[4] = {a0, a1, a2, a3};
#pragma unroll
    for (int k = 0; k < 4; ++k) {
      if (aa[k] && s < NPOST) {
        int orig = P.topi[b * NPRE + p0 + k];
        const float* bb = P.box + ((size_t)b * NBOX + orig) * 7;
        float* ro = rois + ((size_t)b * NPOST + s) * 7;
#pragma unroll
        for (int c2 = 0; c2 < 7; ++c2) ro[c2] = bb[c2];
        const float* cc = P.cls + ((size_t)b * NBOX + orig) * 3;
        float l0 = cc[0], l1 = cc[1], l2 = cc[2];
        float m = fmaxf(l0, fmaxf(l1, l2));
        int lab = (l0 == m) ? 0 : ((l1 == m) ? 1 : 2);
        scores[b * NPOST + s] = m;
        labels[b * NPOST + s] = (float)(lab + 1);
        float* lg = logits + ((size_t)b * NPOST + s) * 3;
        lg[0] = l0; lg[1] = l1; lg[2] = l2;
      }
      s += aa[k];
    }
    for (int p2 = tid; p2 < NPOST; p2 += BLK) {
      if (p2 >= total) {
        float* ro = rois + ((size_t)b * NPOST + p2) * 7;
#pragma unroll
        for (int c2 = 0; c2 < 7; ++c2) ro[c2] = 0.f;
        scores[b * NPOST + p2] = 0.f;
        labels[b * NPOST + p2] = 1.f;
        float* lg = logits + ((size_t)b * NPOST + p2) * 3;
        lg[0] = 0.f; lg[1] = 0.f; lg[2] = 0.f;
      }
    }
  }
}

extern "C" void kernel_launch(void* const* d_in, const int* in_sizes, int n_in,
                              void* d_out, int out_size, void* d_ws, size_t ws_size,
                              hipStream_t stream) {
  int B = in_sizes[0] / (NBOX * 7);    // == 2

  char* w = (char*)d_ws;
  size_t off = 0;
  Params P;
  P.box = (const float*)d_in[0];
  P.cls = (const float*)d_in[1];
  P.out = (float*)d_out;
  P.B = B;
  P.keys    = (ull*)(w + off);      off += (size_t)B * NBOX * sizeof(ull);
  P.hist    = (unsigned*)(w + off); off += (size_t)B * NBUCK * sizeof(unsigned);
  P.cand    = (ull*)(w + off);      off += (size_t)B * NCAND * sizeof(ull);
  P.candCnt = (unsigned*)(w + off); off += 64;
  P.topi    = (int*)(w + off);      off += (size_t)B * NPRE * sizeof(int);
  off = (off + 63) & ~(size_t)63;
  P.binfo   = (float*)(w + off);    off += (size_t)B * NPRE * 16 * sizeof(float);
  P.pinfo   = (float4*)(w + off);   off += (size_t)B * NPRE * sizeof(float4);
  P.mask    = (ull*)(w + off);      off += (size_t)B * NPRE * 16 * sizeof(ull);
  P.nz      = (unsigned*)(w + off); off += (size_t)B * NPRE * sizeof(unsigned);
  P.wcnt    = (unsigned*)(w + off); off += 64;
  P.wl      = (unsigned*)(w + off);
  unsigned wcap = 0;
  if (ws_size > off) {
    size_t rem = (ws_size - off) / sizeof(unsigned);
    wcap = (rem < (size_t)WMAX) ? (unsigned)rem : WMAX;
  }
  P.wcap = wcap;
  (void)out_size; (void)n_in;

  void* args[] = {&P};
  hipLaunchCooperativeKernel((void*)k_all, dim3(GRIDB), dim3(BLK), args, 0, stream);
}

// Round 7
// 155.934 us; speedup vs baseline: 1.8697x; 1.8697x over previous
//
#include <hip/hip_runtime.h>
#include <hip/hip_bf16.h>
#include <math.h>

#define NBOX   16384
#define NPRE   1024
#define NPOST  512
#define NMS_TH 0.8f
#define DEN_EPS 1e-8f
#define NCAND  2048          // top-k candidate buffer
#define NBUCK  8192          // 13-bit histogram buckets
#define WMAX   (1u << 20)    // max worklist entries
#define ROWCAP 128           // LDS-prefetched NMS rows

typedef unsigned long long ull;

__device__ __forceinline__ unsigned mono_f32(float a) {
  unsigned u = __float_as_uint(a);
  return (u & 0x80000000u) ? ~u : (u | 0x80000000u);
}

// ---------------- K1: keys + global histogram (128 blocks) -------------------
// key = (mono(score) << 14) | (16383 - i): u64 '>' == top_k order.
__global__ __launch_bounds__(256) void k_keys(
    const float* __restrict__ cls, ull* __restrict__ keys,
    unsigned* __restrict__ hist) {
  int gid = blockIdx.x * 256 + threadIdx.x;    // over B*NBOX
  int i = gid & (NBOX - 1);
  int b = gid >> 14;
  const float* cc = cls + (size_t)gid * 3;
  float s = fmaxf(cc[0], fmaxf(cc[1], cc[2]));
  unsigned u = mono_f32(s);
  keys[gid] = ((ull)u << 14) | (ull)(16383 - i);
  atomicAdd(&hist[b * NBUCK + (u >> 19)], 1u);
}

// ---------------- K2: per-block redundant threshold + ballot compact ---------
__global__ __launch_bounds__(256) void k_thr(
    const ull* __restrict__ keys, const unsigned* __restrict__ hist,
    ull* __restrict__ cand, unsigned* __restrict__ candCnt) {
  __shared__ unsigned smallu[16];
  int tid = threadIdx.x;
  int gid = blockIdx.x * 256 + tid;
  int lane = tid & 63, wv = tid >> 6;
  int b = gid >> 14;                           // block-uniform (NBOX%256==0)
  const unsigned* hb = hist + b * NBUCK;
  // chunk = 32 buckets/thread; inclusive suffix scan of chunk sums
  unsigned csum = 0;
#pragma unroll 8
  for (int k = 0; k < 32; ++k) csum += hb[tid * 32 + k];
  unsigned v = csum;
#pragma unroll
  for (int off = 1; off < 64; off <<= 1) {
    unsigned o = __shfl_down((int)v, off, 64);
    if (lane + off < 64) v += o;
  }
  if (lane == 0) smallu[wv] = v;
  __syncthreads();
  unsigned shi = 0;
  for (int w2 = wv + 1; w2 < 4; ++w2) shi += smallu[w2];
  unsigned incl = v + shi;                     // suffix incl this chunk
  unsigned safter = incl - csum;               // suffix of higher chunks
  if (safter < NPRE && incl >= NPRE) {         // unique crossing chunk
    unsigned c = safter;
    for (int k = 31; k >= 0; --k) {
      c += hb[tid * 32 + k];
      if (c >= NPRE) { smallu[8] = (unsigned)(tid * 32 + k); break; }
    }
  }
  __syncthreads();
  unsigned T = smallu[8];
  ull key = keys[gid];
  bool c = (unsigned)(key >> 33) >= T;
  ull bal = __ballot(c);
  if (bal) {
    unsigned base = 0;
    if (lane == 0) base = atomicAdd(&candCnt[b], (unsigned)__popcll(bal));
    base = (unsigned)__shfl((int)base, 0, 64);
    if (c) {
      unsigned pos = base + (unsigned)__popcll(bal & ((1ull << lane) - 1ull));
      if (pos < NCAND) cand[(size_t)b * NCAND + pos] = key;
    }
  }
}

// ---------------- K3: rank candidates -> topi, binfo, pinfo ------------------
// binfo row (16 floats): x,y,dx,dy,cos,sin,cx[4],cy[4],circumrad,area
// pinfo[j] = float4(x, y, circumrad, area)
__global__ __launch_bounds__(256) void k_ranksel(
    const float* __restrict__ box, const ull* __restrict__ cand,
    const unsigned* __restrict__ candCnt,
    int* __restrict__ topi, float* __restrict__ binfo, float4* __restrict__ pinfo) {
  __shared__ ull lk[NCAND];
  int b = blockIdx.y;
  int tid = threadIdx.x;
  int j = blockIdx.x * 256 + tid;              // 0..2047
  unsigned C = candCnt[b]; if (C > NCAND) C = NCAND;
#pragma unroll
  for (int k = 0; k < NCAND / 256; ++k) {
    int idx = k * 256 + tid;
    lk[idx] = ((unsigned)idx < C) ? cand[(size_t)b * NCAND + idx] : 0ULL;
  }
  __syncthreads();
  ull my = ((unsigned)j < C) ? lk[j] : 0ULL;
  int r = 0;
  const ulonglong2* p2 = (const ulonglong2*)lk;
#pragma unroll 8
  for (int k = 0; k < NCAND / 2; ++k) {
    ulonglong2 kk = p2[k];
    r += (kk.x > my) ? 1 : 0;
    r += (kk.y > my) ? 1 : 0;
  }
  if ((unsigned)j >= C || r >= NPRE) return;
  int i = 16383 - (int)(my & 0x3FFFULL);
  topi[b * NPRE + r] = i;
  const float* bp = box + ((size_t)b * NBOX + i) * 7;
  float x = bp[0], y = bp[1], dx = bp[3], dy = bp[4], ry = bp[6];
  float c = cosf(ry), s = sinf(ry);
  float* o = binfo + ((size_t)b * NPRE + r) * 16;
  o[0] = x; o[1] = y; o[2] = dx; o[3] = dy; o[4] = c; o[5] = s;
  const float offx[4] = {0.5f, -0.5f, -0.5f, 0.5f};
  const float offy[4] = {0.5f, 0.5f, -0.5f, -0.5f};
#pragma unroll
  for (int k = 0; k < 4; ++k) {
    float lx = dx * offx[k], ly = dy * offy[k];
    o[6 + k]  = x + lx * c - ly * s;
    o[10 + k] = y + lx * s + ly * c;
  }
  float rad = 0.5f * sqrtf(dx * dx + dy * dy);
  float area = dx * dy;
  o[14] = rad; o[15] = area;
  pinfo[(size_t)b * NPRE + r] = make_float4(x, y, rad, area);
}

// ---------------- exact rotated IoU > thresh, register-only ------------------
// Stable argsort by (angle, idx) == successor chain on key=(mono(ang)<<5)|idx;
// polygon area = sum of cross(p, succ(p)), wrap to global min key.
__device__ bool iou_exact_gt(const float* __restrict__ Ab, const float* __restrict__ Bb) {
  float ax = Ab[0], ay = Ab[1], bx = Bb[0], by = Bb[1];
  float aA = Ab[15], aB = Bb[15];
  float acx[4], acy[4], bcx[4], bcy[4];
#pragma unroll
  for (int k = 0; k < 4; ++k) {
    acx[k] = Ab[6 + k]; acy[k] = Ab[10 + k];
    bcx[k] = Bb[6 + k]; bcy[k] = Bb[10 + k];
  }
  float px[24], py[24];
  bool act[24];
#pragma unroll
  for (int p = 0; p < 4; ++p) {
    float A0x = acx[p], A0y = acy[p];
    float DAx = acx[(p + 1) & 3] - A0x, DAy = acy[(p + 1) & 3] - A0y;
#pragma unroll
    for (int q = 0; q < 4; ++q) {
      float B0x = bcx[q], B0y = bcy[q];
      float DBx = bcx[(q + 1) & 3] - B0x, DBy = bcy[(q + 1) & 3] - B0y;
      float den = DAx * DBy - DAy * DBx;
      float dxx = B0x - A0x, dyy = B0y - A0y;
      bool dok = fabsf(den) > DEN_EPS;
      float dens = dok ? den : 1.0f;
      float t = (dxx * DBy - dyy * DBx) / dens;
      float u = (dxx * DAy - dyy * DAx) / dens;
      int k = p * 4 + q;
      px[k] = A0x + t * DAx;
      py[k] = A0y + t * DAy;
      act[k] = dok && t >= 0.f && t <= 1.f && u >= 0.f && u <= 1.f;
    }
  }
  float cA = Ab[4], sA = Ab[5], cB = Bb[4], sB = Bb[5];
#pragma unroll
  for (int k = 0; k < 4; ++k) {       // corners of A in B
    float rx = acx[k] - bx, ry = acy[k] - by;
    float qx =  rx * cB + ry * sB, qy = -rx * sB + ry * cB;
    px[16 + k] = acx[k]; py[16 + k] = acy[k];
    act[16 + k] = (fabsf(qx) <= Bb[2] * 0.5f + 1e-5f) && (fabsf(qy) <= Bb[3] * 0.5f + 1e-5f);
  }
#pragma unroll
  for (int k = 0; k < 4; ++k) {       // corners of B in A
    float rx = bcx[k] - ax, ry = bcy[k] - ay;
    float qx =  rx * cA + ry * sA, qy = -rx * sA + ry * cA;
    px[20 + k] = bcx[k]; py[20 + k] = bcy[k];
    act[20 + k] = (fabsf(qx) <= Ab[2] * 0.5f + 1e-5f) && (fabsf(qy) <= Ab[3] * 0.5f + 1e-5f);
  }
  int cnt = 0; float sx = 0.f, sy = 0.f;
#pragma unroll
  for (int k = 0; k < 24; ++k)
    if (act[k]) { cnt++; sx += px[k]; sy += py[k]; }
  float fc = (float)(cnt > 1 ? cnt : 1);
  float cx0 = sx / fc, cy0 = sy / fc;
  ull key[24];
#pragma unroll
  for (int k = 0; k < 24; ++k) {
    float ang = atan2f(py[k] - cy0, px[k] - cx0);
    key[k] = act[k] ? ((((ull)mono_f32(ang)) << 5) | (ull)k) : ~0ull;
  }
  ull kmin = ~0ull; float fx = 0.f, fy = 0.f;
#pragma unroll
  for (int k = 0; k < 24; ++k) {
    bool lt = key[k] < kmin;
    kmin = lt ? key[k] : kmin;
    fx = lt ? px[k] : fx;
    fy = lt ? py[k] : fy;
  }
  float ssum = 0.f;
#pragma unroll
  for (int k = 0; k < 24; ++k) {
    ull myk = key[k];
    ull best = ~0ull; float nx = fx, ny = fy;   // default: wrap to first
#pragma unroll
    for (int j = 0; j < 24; ++j) {
      bool c = (key[j] > myk) && (key[j] < best);
      best = c ? key[j] : best;
      nx = c ? px[j] : nx;
      ny = c ? py[j] : ny;
    }
    float contrib = px[k] * ny - py[k] * nx;
    ssum += (myk != ~0ull) ? contrib : 0.f;
  }
  float inter = 0.5f * fabsf(ssum);
  float uni = aA + aB - inter;
  return inter / fmaxf(uni, 1e-6f) > NMS_TH;
}

// ---------------- K4: cheap rejects -> compact worklist + mask-word zero -----
__global__ __launch_bounds__(256) void k_pairs(
    const float4* __restrict__ pinfo,
    unsigned* __restrict__ wl, unsigned* __restrict__ wcnt, unsigned wcap,
    ull* __restrict__ mask) {
  int wv = (blockIdx.x * 256 + threadIdx.x) >> 6;
  int lane = threadIdx.x & 63;
  int w = wv & 15;
  int i = (wv >> 4) & (NPRE - 1);
  int b = wv >> 14;
  if (w * 64 + 63 <= i) return;                // wave-uniform: all j <= i
  int j = w * 64 + lane;
  float4 pj = pinfo[(size_t)b * NPRE + j];     // coalesced 16B/lane
  float4 pi = pinfo[(size_t)b * NPRE + i];     // broadcast
  bool cnd = false;
  if (j > i) {
    float ddx = pi.x - pj.x, ddy = pi.y - pj.y;
    float rr = pi.z + pj.z + 1e-3f;
    if (ddx * ddx + ddy * ddy <= rr * rr) {    // not provably disjoint
      float mn = fminf(pi.w, pj.w), mx = fmaxf(pi.w, pj.w);
      if (mn > NMS_TH * mx) cnd = true;        // not provably iou<=0.8
    }
  }
  ull bal = __ballot(cnd);
  if (!bal) return;
  unsigned base = 0;
  if (lane == 0) {
    mask[((size_t)b * NPRE + i) * 16 + w] = 0ull;   // pre-zero word (nz-gated)
    base = atomicAdd(wcnt, (unsigned)__popcll(bal));
  }
  base = (unsigned)__shfl((int)base, 0, 64);
  if (cnd) {
    unsigned off = base + (unsigned)__popcll(bal & ((1ull << lane) - 1ull));
    if (off < wcap)
      wl[off] = ((unsigned)b << 20) | ((unsigned)i << 10) | (unsigned)j;
  }
}

// ---------------- K5: exact IoU over dense worklist --------------------------
__global__ __launch_bounds__(256) void k_iou(
    const float* __restrict__ binfo, const unsigned* __restrict__ wl,
    const unsigned* __restrict__ wcnt, unsigned wcap,
    ull* __restrict__ mask, unsigned* __restrict__ nz) {
  unsigned n = wcnt[0];
  if (n > wcap) n = wcap;
  unsigned stride = gridDim.x * 256;
  for (unsigned t = blockIdx.x * 256 + threadIdx.x; t < n; t += stride) {
    unsigned pk = wl[t];
    unsigned b = pk >> 20, i = (pk >> 10) & 1023, j = pk & 1023;
    const float* base = binfo + (size_t)b * NPRE * 16;
    if (iou_exact_gt(base + (size_t)i * 16, base + (size_t)j * 16)) {
      atomicOr(&mask[((size_t)b * NPRE + i) * 16 + (j >> 6)], 1ull << (j & 63));
      atomicOr(&nz[b * NPRE + i], 1u << (j >> 6));
    }
  }
}

// ---------------- K6: NMS (LDS-prefetched walk) + compact + gather -----------
__global__ __launch_bounds__(256) void k_final(
    const float* __restrict__ box, const float* __restrict__ cls,
    const int* __restrict__ topi, const ull* __restrict__ mask,
    const unsigned* __restrict__ nz, float* __restrict__ out, int B) {
  __shared__ ull lk[ROWCAP * 16];      // 16 KB prefetched mask rows
  __shared__ ull remv_sh[16];
  __shared__ unsigned smallu[16];
  __shared__ unsigned rlist[ROWCAP];
  __shared__ unsigned rn_sh;
  int b = blockIdx.x;
  int tid = threadIdx.x;               // 0..255
  int lane = tid & 63, wv = tid >> 6;

  if (wv == 0) {                       // wave 0: interesting-row list
    ull rfr[16];
#pragma unroll
    for (int w = 0; w < 16; ++w) {
      unsigned vz = nz[b * NPRE + w * 64 + lane];
      rfr[w] = __ballot(vz != 0u);
    }
    if (lane == 0) {
      unsigned n = 0;
      for (int w = 0; w < 16; ++w) {
        ull bb = rfr[w];
        while (bb) {
          int ii = __ffsll(bb) - 1;
          bb &= bb - 1;
          if (n < ROWCAP) rlist[n] = (unsigned)(w * 64 + ii);
          n++;
        }
      }
      rn_sh = n;
    }
  }
  __syncthreads();
  unsigned rn = rn_sh;
  unsigned rpf = rn < ROWCAP ? rn : ROWCAP;
  for (unsigned s = (unsigned)(tid >> 4); s < rpf; s += 256 / 16) {
    unsigned row = rlist[s];
    int wd = tid & 15;
    unsigned nzi = nz[b * NPRE + row];
    lk[s * 16 + wd] = ((nzi >> wd) & 1u)
                      ? mask[((size_t)b * NPRE + row) * 16 + wd] : 0ull;
  }
  __syncthreads();
  if (wv == 0) {                       // wave 0: serial greedy walk (LDS speed)
    ull remv = 0;                      // lane w<16 holds remv word w
    for (unsigned s = 0; s < rn; ++s) {
      unsigned row;
      ull m;
      if (s < ROWCAP) {
        row = rlist[s];
        m = (lane < 16) ? lk[s * 16 + lane] : 0ull;
      } else {                         // overflow: find s-th row, global reads
        unsigned cnt2 = 0; row = 0;
        for (int w = 0; w < 16 && cnt2 <= s; ++w) {
          ull bb = __ballot(nz[b * NPRE + w * 64 + lane] != 0u);
          unsigned pc = (unsigned)__popcll(bb);
          if (cnt2 + pc > s) {
            unsigned need = s - cnt2;
            ull t2 = bb;
            for (unsigned q = 0; q < need; ++q) t2 &= t2 - 1;
            row = w * 64 + (__ffsll(t2) - 1);
            cnt2 = s + 1; break;
          }
          cnt2 += pc;
        }
        unsigned nzi = nz[b * NPRE + row];
        m = (lane < 16 && ((nzi >> lane) & 1u))
            ? mask[((size_t)b * NPRE + row) * 16 + lane] : 0ull;
      }
      int w = row >> 6, ii = row & 63;
      ull rw = __shfl(remv, w, 64);
      if (!((rw >> ii) & 1ULL)) remv |= m;
    }
    if (lane < 16) remv_sh[lane] = remv;
  }
  __syncthreads();

  // compact + gather: 256 threads x 4 contiguous slots
  int p0 = tid * 4;
  ull rw = remv_sh[p0 >> 6];
  int a0 = !((rw >> ((p0 + 0) & 63)) & 1ULL);
  int a1 = !((rw >> ((p0 + 1) & 63)) & 1ULL);
  int a2 = !((rw >> ((p0 + 2) & 63)) & 1ULL);
  int a3 = !((rw >> ((p0 + 3) & 63)) & 1ULL);
  int myc = a0 + a1 + a2 + a3;
  int v = myc;
#pragma unroll
  for (int off = 1; off < 64; off <<= 1) {
    int t2 = __shfl_up(v, off, 64);
    if (lane >= off) v += t2;
  }
  if (lane == 63) smallu[wv] = (unsigned)v;
  __syncthreads();
  int pre = 0;
  for (int w2 = 0; w2 < wv; ++w2) pre += (int)smallu[w2];
  int total = (int)(smallu[0] + smallu[1] + smallu[2] + smallu[3]);
  int s = pre + v - myc;

  float* rois   = out;
  float* scores = out + (size_t)B * NPOST * 7;
  float* labels = scores + (size_t)B * NPOST;
  float* logits = labels + (size_t)B * NPOST;
  int aa[4] = {a0, a1, a2, a3};
#pragma unroll
  for (int k = 0; k < 4; ++k) {
    if (aa[k] && s < NPOST) {
      int orig = topi[b * NPRE + p0 + k];
      const float* bb = box + ((size_t)b * NBOX + orig) * 7;
      float* ro = rois + ((size_t)b * NPOST + s) * 7;
#pragma unroll
      for (int c2 = 0; c2 < 7; ++c2) ro[c2] = bb[c2];
      const float* cc = cls + ((size_t)b * NBOX + orig) * 3;
      float l0 = cc[0], l1 = cc[1], l2 = cc[2];
      float m = fmaxf(l0, fmaxf(l1, l2));
      int lab = (l0 == m) ? 0 : ((l1 == m) ? 1 : 2);  // argmax: first max
      scores[b * NPOST + s] = m;
      labels[b * NPOST + s] = (float)(lab + 1);
      float* lg = logits + ((size_t)b * NPOST + s) * 3;
      lg[0] = l0; lg[1] = l1; lg[2] = l2;
    }
    s += aa[k];
  }
  for (int p2 = tid; p2 < NPOST; p2 += 256) {
    if (p2 >= total) {                 // invalid slots: zeros, label 1
      float* ro = rois + ((size_t)b * NPOST + p2) * 7;
#pragma unroll
      for (int c2 = 0; c2 < 7; ++c2) ro[c2] = 0.f;
      scores[b * NPOST + p2] = 0.f;
      labels[b * NPOST + p2] = 1.f;
      float* lg = logits + ((size_t)b * NPOST + p2) * 3;
      lg[0] = 0.f; lg[1] = 0.f; lg[2] = 0.f;
    }
  }
}

extern "C" void kernel_launch(void* const* d_in, const int* in_sizes, int n_in,
                              void* d_out, int out_size, void* d_ws, size_t ws_size,
                              hipStream_t stream) {
  const float* box = (const float*)d_in[0];
  const float* cls = (const float*)d_in[1];
  float* out = (float*)d_out;
  int B = in_sizes[0] / (NBOX * 7);    // == 2

  char* w = (char*)d_ws;
  size_t off = 0;
  // --- contiguous zero region: nz | candCnt | wcnt | hist ---
  char* zbase      = w;
  unsigned* nz     = (unsigned*)(w + off); off += (size_t)B * NPRE * sizeof(unsigned);
  unsigned* candCt = (unsigned*)(w + off); off += 64;
  unsigned* wcnt   = (unsigned*)(w + off); off += 64;
  unsigned* hist   = (unsigned*)(w + off); off += (size_t)B * NBUCK * sizeof(unsigned);
  size_t zbytes = off;
  // --- rest ---
  ull* keys        = (ull*)(w + off);      off += (size_t)B * NBOX * sizeof(ull);
  ull* cand        = (ull*)(w + off);      off += (size_t)B * NCAND * sizeof(ull);
  int* topi        = (int*)(w + off);      off += (size_t)B * NPRE * sizeof(int);
  off = (off + 63) & ~(size_t)63;
  float* binfo     = (float*)(w + off);    off += (size_t)B * NPRE * 16 * sizeof(float);
  float4* pinfo    = (float4*)(w + off);   off += (size_t)B * NPRE * sizeof(float4);
  ull* mask        = (ull*)(w + off);      off += (size_t)B * NPRE * 16 * sizeof(ull);
  unsigned* wl     = (unsigned*)(w + off);
  unsigned wcap = 0;
  if (ws_size > off) {
    size_t rem = (ws_size - off) / sizeof(unsigned);
    wcap = (rem < (size_t)WMAX) ? (unsigned)rem : WMAX;
  }
  (void)out_size; (void)n_in;

  hipMemsetAsync(zbase, 0, zbytes, stream);
  hipLaunchKernelGGL(k_keys,    dim3(B * NBOX / 256), dim3(256), 0, stream, cls, keys, hist);
  hipLaunchKernelGGL(k_thr,     dim3(B * NBOX / 256), dim3(256), 0, stream, keys, hist, cand, candCt);
  hipLaunchKernelGGL(k_ranksel, dim3(NCAND / 256, B), dim3(256), 0, stream, box, cand, candCt, topi, binfo, pinfo);
  hipLaunchKernelGGL(k_pairs,   dim3(B * NPRE * 16 / 4), dim3(256), 0, stream, pinfo, wl, wcnt, wcap, mask);
  hipLaunchKernelGGL(k_iou,     dim3(128), dim3(256), 0, stream, binfo, wl, wcnt, wcap, mask, nz);
  hipLaunchKernelGGL(k_final,   dim3(B), dim3(256), 0, stream, box, cls, topi, mask, nz, out, B);
}